// Round 1
// baseline (250.858 us; speedup 1.0000x reference)
//
#include <hip/hip_runtime.h>

static constexpr float ALPHA = 0.1f;

__device__ __forceinline__ void bl_setup(float tc, int S, int& i0, int& i1, float& w) {
    // pixel coord exactly as reference: p = tc*S - 0.5
    float p = tc * (float)S - 0.5f;
    float pf = floorf(p);
    w = p - pf;
    int i = (int)pf;
    i0 = min(max(i, 0), S - 1);
    i1 = min(max(i + 1, 0), S - 1);
}

__device__ __forceinline__ float bilin(const float* __restrict__ t,
                                       int rowA, int rowB, float wy,
                                       int xa, int xb, float wx) {
    float v00 = t[rowA + xa];
    float v01 = t[rowA + xb];
    float v10 = t[rowB + xa];
    float v11 = t[rowB + xb];
    float top = v00 * (1.0f - wx) + v01 * wx;
    float bot = v10 * (1.0f - wx) + v11 * wx;
    return top * (1.0f - wy) + bot * wy;
}

__global__ __launch_bounds__(256) void taa_kernel(
    const float* __restrict__ x, const float* __restrict__ mv,
    const float* __restrict__ hist, float* __restrict__ out,
    int N, int C, int H, int W)
{
    const int w = blockIdx.x * 64 + (threadIdx.x & 63);
    const int h = blockIdx.y * 4 + (threadIdx.x >> 6);
    const int n = blockIdx.z;
    if (w >= W || h >= H) return;

    const int chanStride = H * W;                 // 2,073,600
    const int pix = h * W + w;
    const int nhw = n * chanStride + pix;

    // --- motion vector (coalesced float2) ---
    const float2 g = ((const float2*)mv)[nhw];

    // --- per-axis bicubic setup (Catmull-Rom, matches reference exactly) ---
    // X axis
    float posx  = (g.x + 1.0f) * 0.5f * (float)W;
    float cposx = floorf(posx - 0.5f) + 0.5f;
    float fxv   = posx - cposx;
    float fx2 = fxv * fxv, fx3 = fx2 * fxv;
    float w0x  = -0.5f * fx3 + fx2 - 0.5f * fxv;
    float w2x  = -1.5f * fx3 + 2.0f * fx2 + 0.5f * fxv;
    float w3x  =  0.5f * fx3 - 0.5f * fx2;
    float w12x = (1.5f * fx3 - 2.5f * fx2 + 1.0f) + w2x;
    float rwx  = 1.0f / (float)W;
    float tcx12 = rwx * (cposx + w2x / w12x);
    float tcx0  = rwx * (cposx - 1.0f);
    float tcx3  = rwx * (cposx + 2.0f);
    // Y axis
    float posy  = (g.y + 1.0f) * 0.5f * (float)H;
    float cposy = floorf(posy - 0.5f) + 0.5f;
    float fyv   = posy - cposy;
    float fy2 = fyv * fyv, fy3 = fy2 * fyv;
    float w0y  = -0.5f * fy3 + fy2 - 0.5f * fyv;
    float w2y  = -1.5f * fy3 + 2.0f * fy2 + 0.5f * fyv;
    float w3y  =  0.5f * fy3 - 0.5f * fy2;
    float w12y = (1.5f * fy3 - 2.5f * fy2 + 1.0f) + w2y;
    float rwy  = 1.0f / (float)H;
    float tcy12 = rwy * (cposy + w2y / w12y);
    float tcy0  = rwy * (cposy - 1.0f);
    float tcy3  = rwy * (cposy + 2.0f);

    // --- bilinear footprints (channel-independent) ---
    int x12a, x12b; float tx12; bl_setup(tcx12, W, x12a, x12b, tx12);
    int x0a,  x0b;  float tx0;  bl_setup(tcx0,  W, x0a,  x0b,  tx0);
    int x3a,  x3b;  float tx3;  bl_setup(tcx3,  W, x3a,  x3b,  tx3);
    int y12a, y12b; float ty12; bl_setup(tcy12, H, y12a, y12b, ty12);
    int y0a,  y0b;  float ty0;  bl_setup(tcy0,  H, y0a,  y0b,  ty0);
    int y3a,  y3b;  float ty3;  bl_setup(tcy3,  H, y3a,  y3b,  ty3);

    const int rY12a = y12a * W, rY12b = y12b * W;
    const int rY0a  = y0a  * W, rY0b  = y0b  * W;
    const int rY3a  = y3a  * W, rY3b  = y3b  * W;

    // --- scalar tap weights ---
    float ww1 = w12x * w0y;
    float ww2 = w0x  * w12y;
    float ww3 = w3x  * w12y;
    float ww4 = w12x * w3y;
    float ww5 = w12x * w12y;
    float rrec = 1.0f / (ww1 + ww2 + ww3 + ww4 + ww5);

    // --- 3x3 neighborhood indices (clamped == SAME/-inf for min/max) ---
    const int hm = max(h - 1, 0), hp = min(h + 1, H - 1);
    const int wm = max(w - 1, 0), wp = min(w + 1, W - 1);
    const int rM = hm * W, r0 = h * W, rP = hp * W;

    const float* xn = x    + n * C * chanStride;
    const float* hn = hist + n * C * chanStride;
    float*       on = out  + n * C * chanStride;

#pragma unroll
    for (int c = 0; c < 3; ++c) {
        const float* hc = hn + c * chanStride;
        float s1 = bilin(hc, rY0a,  rY0b,  ty0,  x12a, x12b, tx12);
        float s2 = bilin(hc, rY12a, rY12b, ty12, x0a,  x0b,  tx0);
        float s3 = bilin(hc, rY12a, rY12b, ty12, x3a,  x3b,  tx3);
        float s4 = bilin(hc, rY3a,  rY3b,  ty3,  x12a, x12b, tx12);
        float s5 = bilin(hc, rY12a, rY12b, ty12, x12a, x12b, tx12);
        float reproj = (s1 * ww1 + s2 * ww2 + s3 * ww3 + s4 * ww4 + s5 * ww5) * rrec;

        const float* xc = xn + c * chanStride;
        float a0 = xc[rM + wm], a1 = xc[rM + w], a2 = xc[rM + wp];
        float b0 = xc[r0 + wm], b1 = xc[r0 + w], b2 = xc[r0 + wp];
        float c0 = xc[rP + wm], c1 = xc[rP + w], c2 = xc[rP + wp];

        float mx = fmaxf(fmaxf(fmaxf(a0, a1), fmaxf(a2, b0)),
                         fmaxf(fmaxf(b1, b2), fmaxf(fmaxf(c0, c1), c2)));
        float mn = fminf(fminf(fminf(a0, a1), fminf(a2, b0)),
                         fminf(fminf(b1, b2), fminf(fminf(c0, c1), c2)));

        reproj = fminf(fmaxf(reproj, mn), mx);
        on[c * chanStride + pix] = ALPHA * b1 + (1.0f - ALPHA) * reproj;
    }
}

extern "C" void kernel_launch(void* const* d_in, const int* in_sizes, int n_in,
                              void* d_out, int out_size, void* d_ws, size_t ws_size,
                              hipStream_t stream) {
    const float* x    = (const float*)d_in[0];
    const float* mv   = (const float*)d_in[1];
    const float* hist = (const float*)d_in[2];
    float* out = (float*)d_out;

    const int N = 2, C = 3, H = 1080, W = 1920;
    dim3 block(256, 1, 1);
    dim3 grid((W + 63) / 64, (H + 3) / 4, N);
    taa_kernel<<<grid, block, 0, stream>>>(x, mv, hist, out, N, C, H, W);
}

// Round 2
// 159.241 us; speedup vs baseline: 1.5753x; 1.5753x over previous
//
#include <hip/hip_runtime.h>

static constexpr float ALPHA = 0.1f;

#define TW 64
#define TH 4
#define HWC 66   // halo width  (TW+2)
#define HHC 6    // halo height (TH+2)
#define LPAD 68  // padded LDS row stride

__device__ __forceinline__ int iclamp(int v, int lo, int hi) {
    return min(max(v, lo), hi);
}

__global__ __launch_bounds__(256, 4) void taa_kernel(
    const float* __restrict__ x, const float* __restrict__ mv,
    const float* __restrict__ hist, float* __restrict__ out,
    int N, int H, int W)
{
    __shared__ float Lx[3][HHC][LPAD];

    const int lx = threadIdx.x & 63;
    const int ly = threadIdx.x >> 6;
    const int w0 = blockIdx.x * TW;
    const int h0 = blockIdx.y * TH;
    const int n  = blockIdx.z;
    const int HW = H * W;

    // ---- Phase 1: cooperative LDS stage of x tile + 1-px halo (all 3 ch) ----
    {
        const float* xn = x + n * 3 * HW;
        for (int i = threadIdx.x; i < 3 * HHC * HWC; i += 256) {
            int rowid = i / HWC;          // 0..17
            int col   = i - rowid * HWC;  // 0..65
            int c     = rowid / HHC;      // 0..2
            int r     = rowid - c * HHC;  // 0..5
            int gr = iclamp(h0 - 1 + r, 0, H - 1);
            int gc = iclamp(w0 - 1 + col, 0, W - 1);
            Lx[c][r][col] = xn[c * HW + gr * W + gc];
        }
    }

    const int w = w0 + lx;
    const int h = h0 + ly;
    const int pix = h * W + w;

    // ---- Phase 2: mv load + bicubic setup (channel-independent) ----
    const float2 g = ((const float2*)mv)[n * HW + pix];

    // X axis
    float posx = (g.x + 1.0f) * 0.5f * (float)W;
    float pxm  = floorf(posx - 0.5f);            // mx as float
    float fxv  = posx - (pxm + 0.5f);
    float fx2 = fxv * fxv, fx3 = fx2 * fxv;
    float w0x  = -0.5f * fx3 + fx2 - 0.5f * fxv;
    float w2x  = -1.5f * fx3 + 2.0f * fx2 + 0.5f * fxv;
    float w3x  =  0.5f * fx3 - 0.5f * fx2;
    float w12x = (1.5f * fx3 - 2.5f * fx2 + 1.0f) + w2x;
    float p12x = pxm + w2x / w12x;               // pixel coord of fractional tap
    float fl12x = floorf(p12x);
    float tx = p12x - fl12x;
    int   mx_ = (int)pxm;
    int   i12x = (int)fl12x;
    // Y axis
    float posy = (g.y + 1.0f) * 0.5f * (float)H;
    float pym  = floorf(posy - 0.5f);
    float fyv  = posy - (pym + 0.5f);
    float fy2 = fyv * fyv, fy3 = fy2 * fyv;
    float w0y  = -0.5f * fy3 + fy2 - 0.5f * fyv;
    float w2y  = -1.5f * fy3 + 2.0f * fy2 + 0.5f * fyv;
    float w3y  =  0.5f * fy3 - 0.5f * fy2;
    float w12y = (1.5f * fy3 - 2.5f * fy2 + 1.0f) + w2y;
    float p12y = pym + w2y / w12y;
    float fl12y = floorf(p12y);
    float ty = p12y - fl12y;
    int   my_ = (int)pym;
    int   i12y = (int)fl12y;

    // column / row indices (clamped)
    const int c12a = iclamp(i12x,     0, W - 1);
    const int c12b = iclamp(i12x + 1, 0, W - 1);
    const int ca   = iclamp(mx_ - 1,  0, W - 1);
    const int cb   = iclamp(mx_ + 2,  0, W - 1);
    const int r12a = iclamp(i12y,     0, H - 1);
    const int r12b = iclamp(i12y + 1, 0, H - 1);
    const int ra   = iclamp(my_ - 1,  0, H - 1);
    const int rb   = iclamp(my_ + 2,  0, H - 1);

    // scalar tap weights
    float ww1 = w12x * w0y;
    float ww2 = w0x  * w12y;
    float ww3 = w3x  * w12y;
    float ww4 = w12x * w3y;
    float ww5 = w12x * w12y;
    float rrec = 1.0f / (ww1 + ww2 + ww3 + ww4 + ww5);

    // ---- Phase 3: issue all 36 history loads (independent, batched) ----
    const float* hn = hist + n * 3 * HW;
    float t[3][12];
#pragma unroll
    for (int c = 0; c < 3; ++c) {
        const float* hc  = hn + c * HW;
        const float* pRa = hc + ra   * W;
        const float* pR1 = hc + r12a * W;
        const float* pR2 = hc + r12b * W;
        const float* pRb = hc + rb   * W;
        t[c][0]  = pRa[c12a];  t[c][1]  = pRa[c12b];
        t[c][2]  = pR1[ca];    t[c][3]  = pR1[c12a];
        t[c][4]  = pR1[c12b];  t[c][5]  = pR1[cb];
        t[c][6]  = pR2[ca];    t[c][7]  = pR2[c12a];
        t[c][8]  = pR2[c12b];  t[c][9]  = pR2[cb];
        t[c][10] = pRb[c12a];  t[c][11] = pRb[c12b];
    }

    __syncthreads();

    // ---- Phase 4: per-channel combine + neighborhood clamp + blend ----
    float* on = out + n * 3 * HW;
    const float omtx = 1.0f - tx;
    const float omty = 1.0f - ty;
#pragma unroll
    for (int c = 0; c < 3; ++c) {
        float s1 = t[c][0] * omtx + t[c][1] * tx;                 // row my-1
        float s4 = t[c][10] * omtx + t[c][11] * tx;               // row my+2
        float s2 = t[c][2] * omty + t[c][6] * ty;                 // col mx-1
        float s3 = t[c][5] * omty + t[c][9] * ty;                 // col mx+2
        float top5 = t[c][3] * omtx + t[c][4] * tx;
        float bot5 = t[c][7] * omtx + t[c][8] * tx;
        float s5 = top5 * omty + bot5 * ty;
        float reproj = (s1 * ww1 + s2 * ww2 + s3 * ww3 + s4 * ww4 + s5 * ww5) * rrec;

        float a0 = Lx[c][ly  ][lx  ], a1 = Lx[c][ly  ][lx+1], a2 = Lx[c][ly  ][lx+2];
        float b0 = Lx[c][ly+1][lx  ], b1 = Lx[c][ly+1][lx+1], b2 = Lx[c][ly+1][lx+2];
        float d0 = Lx[c][ly+2][lx  ], d1 = Lx[c][ly+2][lx+1], d2 = Lx[c][ly+2][lx+2];

        float mxv = fmaxf(fmaxf(fmaxf(a0, a1), fmaxf(a2, b0)),
                          fmaxf(fmaxf(b1, b2), fmaxf(fmaxf(d0, d1), d2)));
        float mnv = fminf(fminf(fminf(a0, a1), fminf(a2, b0)),
                          fminf(fminf(b1, b2), fminf(fminf(d0, d1), d2)));

        reproj = fminf(fmaxf(reproj, mnv), mxv);
        on[c * HW + pix] = ALPHA * b1 + (1.0f - ALPHA) * reproj;
    }
}

extern "C" void kernel_launch(void* const* d_in, const int* in_sizes, int n_in,
                              void* d_out, int out_size, void* d_ws, size_t ws_size,
                              hipStream_t stream) {
    const float* x    = (const float*)d_in[0];
    const float* mv   = (const float*)d_in[1];
    const float* hist = (const float*)d_in[2];
    float* out = (float*)d_out;

    const int N = 2, H = 1080, W = 1920;
    dim3 block(256, 1, 1);
    dim3 grid(W / TW, H / TH, N);   // 1920%64==0, 1080%4==0 — no partial tiles
    taa_kernel<<<grid, block, 0, stream>>>(x, mv, hist, out, N, H, W);
}

// Round 3
// 90.815 us; speedup vs baseline: 2.7623x; 1.7535x over previous
//
#include <hip/hip_runtime.h>

static constexpr float ALPHA = 0.1f;

#define TW 64
#define TH 4
// x tile:    3ch x 6 rows x 66 cols (stride 68)
#define XROWS 6
#define XCOLS 66
#define XPAD  68
// hist tile: 3ch x 12 rows x 76 cols (stride 80)
// rows h0-4 .. h0+7 (dy in [-2.7,2.7) -> taps within [h-4, h+4])
// cols w0-6 .. w0+69 (dx in [-4.8,4.8) -> taps within [w-6, w+6])
#define HROWS 12
#define HCOLS 76
#define HPAD  80

__device__ __forceinline__ int iclamp(int v, int lo, int hi) {
    return min(max(v, lo), hi);
}

__global__ __launch_bounds__(256, 4) void taa_kernel(
    const float* __restrict__ x, const float* __restrict__ mv,
    const float* __restrict__ hist, float* __restrict__ out,
    int N, int H, int W)
{
    __shared__ float Lx[3][XROWS][XPAD];
    __shared__ float Lh[3][HROWS][HPAD];

    const int lx = threadIdx.x & 63;
    const int ly = threadIdx.x >> 6;
    const int w0 = blockIdx.x * TW;
    const int h0 = blockIdx.y * TH;
    const int n  = blockIdx.z;
    const int HW = H * W;

    const int w = w0 + lx;
    const int h = h0 + ly;
    const int pix = h * W + w;

    // ---- mv load first (VMEM in flight during staging setup) ----
    const float2 g = ((const float2*)mv)[n * HW + pix];

    // ---- Phase 1a: stage history window (coalesced) ----
    {
        const float* hn = hist + n * 3 * HW;
        float* LhF = &Lh[0][0][0];
        for (int i = threadIdx.x; i < 3 * HROWS * HPAD; i += 256) {
            int row = i / HPAD;           // 0..35
            int col = i - row * HPAD;     // 0..79
            if (col < HCOLS) {
                int c = row / HROWS;
                int r = row - c * HROWS;
                int gr = iclamp(h0 - 4 + r, 0, H - 1);
                int gc = iclamp(w0 - 6 + col, 0, W - 1);
                LhF[i] = hn[c * HW + gr * W + gc];
            }
        }
    }
    // ---- Phase 1b: stage x tile + 1px halo ----
    {
        const float* xn = x + n * 3 * HW;
        for (int i = threadIdx.x; i < 3 * XROWS * XCOLS; i += 256) {
            int rowid = i / XCOLS;
            int col   = i - rowid * XCOLS;
            int c     = rowid / XROWS;
            int r     = rowid - c * XROWS;
            int gr = iclamp(h0 - 1 + r, 0, H - 1);
            int gc = iclamp(w0 - 1 + col, 0, W - 1);
            Lx[c][r][col] = xn[c * HW + gr * W + gc];
        }
    }

    // ---- Phase 2: bicubic setup (overlaps staging loads) ----
    // X axis
    float posx = (g.x + 1.0f) * 0.5f * (float)W;
    float pxm  = floorf(posx - 0.5f);
    float fxv  = posx - (pxm + 0.5f);
    float fx2 = fxv * fxv, fx3 = fx2 * fxv;
    float w0x  = -0.5f * fx3 + fx2 - 0.5f * fxv;
    float w2x  = -1.5f * fx3 + 2.0f * fx2 + 0.5f * fxv;
    float w3x  =  0.5f * fx3 - 0.5f * fx2;
    float w12x = (1.5f * fx3 - 2.5f * fx2 + 1.0f) + w2x;
    float p12x = pxm + w2x / w12x;
    float fl12x = floorf(p12x);
    float tx = p12x - fl12x;
    int   mx_  = (int)pxm;
    int   i12x = (int)fl12x;
    // Y axis
    float posy = (g.y + 1.0f) * 0.5f * (float)H;
    float pym  = floorf(posy - 0.5f);
    float fyv  = posy - (pym + 0.5f);
    float fy2 = fyv * fyv, fy3 = fy2 * fyv;
    float w0y  = -0.5f * fy3 + fy2 - 0.5f * fyv;
    float w2y  = -1.5f * fy3 + 2.0f * fy2 + 0.5f * fyv;
    float w3y  =  0.5f * fy3 - 0.5f * fy2;
    float w12y = (1.5f * fy3 - 2.5f * fy2 + 1.0f) + w2y;
    float p12y = pym + w2y / w12y;
    float fl12y = floorf(p12y);
    float ty = p12y - fl12y;
    int   my_  = (int)pym;
    int   i12y = (int)fl12y;

    // local (window-relative) indices from UNclamped taps; border clamp is
    // baked into the staged values. Safety clamp covers ULP-level floor flips.
    const int lrA = iclamp(my_ - 1  - h0 + 4, 0, HROWS - 1);
    const int lr1 = iclamp(i12y     - h0 + 4, 0, HROWS - 1);
    const int lr2 = iclamp(i12y + 1 - h0 + 4, 0, HROWS - 1);
    const int lrB = iclamp(my_ + 2  - h0 + 4, 0, HROWS - 1);
    const int lcA = iclamp(mx_ - 1  - w0 + 6, 0, HCOLS - 1);
    const int lc1 = iclamp(i12x     - w0 + 6, 0, HCOLS - 1);
    const int lc2 = iclamp(i12x + 1 - w0 + 6, 0, HCOLS - 1);
    const int lcB = iclamp(mx_ + 2  - w0 + 6, 0, HCOLS - 1);

    float ww1 = w12x * w0y;
    float ww2 = w0x  * w12y;
    float ww3 = w3x  * w12y;
    float ww4 = w12x * w3y;
    float ww5 = w12x * w12y;
    float rrec = 1.0f / (ww1 + ww2 + ww3 + ww4 + ww5);

    __syncthreads();

    // ---- Phase 3: per-channel combine from LDS ----
    float* on = out + n * 3 * HW;
    const float omtx = 1.0f - tx;
    const float omty = 1.0f - ty;
#pragma unroll
    for (int c = 0; c < 3; ++c) {
        const float* rA = &Lh[c][lrA][0];
        const float* r1 = &Lh[c][lr1][0];
        const float* r2 = &Lh[c][lr2][0];
        const float* rB = &Lh[c][lrB][0];
        float s1   = rA[lc1] * omtx + rA[lc2] * tx;
        float s4   = rB[lc1] * omtx + rB[lc2] * tx;
        float s2   = r1[lcA] * omty + r2[lcA] * ty;
        float s3   = r1[lcB] * omty + r2[lcB] * ty;
        float top5 = r1[lc1] * omtx + r1[lc2] * tx;
        float bot5 = r2[lc1] * omtx + r2[lc2] * tx;
        float s5   = top5 * omty + bot5 * ty;
        float reproj = (s1 * ww1 + s2 * ww2 + s3 * ww3 + s4 * ww4 + s5 * ww5) * rrec;

        float a0 = Lx[c][ly  ][lx  ], a1 = Lx[c][ly  ][lx+1], a2 = Lx[c][ly  ][lx+2];
        float b0 = Lx[c][ly+1][lx  ], b1 = Lx[c][ly+1][lx+1], b2 = Lx[c][ly+1][lx+2];
        float d0 = Lx[c][ly+2][lx  ], d1 = Lx[c][ly+2][lx+1], d2 = Lx[c][ly+2][lx+2];

        float mxv = fmaxf(fmaxf(fmaxf(a0, a1), fmaxf(a2, b0)),
                          fmaxf(fmaxf(b1, b2), fmaxf(fmaxf(d0, d1), d2)));
        float mnv = fminf(fminf(fminf(a0, a1), fminf(a2, b0)),
                          fminf(fminf(b1, b2), fminf(fminf(d0, d1), d2)));

        reproj = fminf(fmaxf(reproj, mnv), mxv);
        on[c * HW + pix] = ALPHA * b1 + (1.0f - ALPHA) * reproj;
    }
}

extern "C" void kernel_launch(void* const* d_in, const int* in_sizes, int n_in,
                              void* d_out, int out_size, void* d_ws, size_t ws_size,
                              hipStream_t stream) {
    const float* x    = (const float*)d_in[0];
    const float* mv   = (const float*)d_in[1];
    const float* hist = (const float*)d_in[2];
    float* out = (float*)d_out;

    const int N = 2, H = 1080, W = 1920;
    dim3 block(256, 1, 1);
    dim3 grid(W / TW, H / TH, N);   // 1920%64==0, 1080%4==0 — no partial tiles
    taa_kernel<<<grid, block, 0, stream>>>(x, mv, hist, out, N, H, W);
}

// Round 4
// 54.015 us; speedup vs baseline: 4.6443x; 1.6813x over previous
//
#include <hip/hip_runtime.h>

static constexpr float ALPHA = 0.1f;

#define TW 64
#define TH 8
// hist window: rows h0-4 .. h0+TH+3 (16 rows), cols w0-8 .. w0+71 (80 cols)
// jitter: |dx| < 4.8 px, |dy| < 2.7 px -> taps within [w-6,w+6] x [h-4,h+4]
#define HROWS 16
#define HCOLS 80   // stride 80 floats = 20 float4 (16B-aligned rows)

__device__ __forceinline__ int iclamp(int v, int lo, int hi) { return min(max(v, lo), hi); }

struct Setup {
    int mA, m1, m2, mB;   // global tap coords (unclamped)
    float t, w0, w3, w12;
};

__device__ __forceinline__ Setup axis_setup(float gcoord, float S) {
    Setup s;
    float pos = (gcoord + 1.0f) * 0.5f * S;
    float pm  = floorf(pos - 0.5f);
    float f   = pos - (pm + 0.5f);
    float f2 = f * f, f3 = f2 * f;
    s.w0  = -0.5f * f3 + f2 - 0.5f * f;
    float w2 = -1.5f * f3 + 2.0f * f2 + 0.5f * f;
    s.w3  =  0.5f * f3 - 0.5f * f2;
    s.w12 = (1.5f * f3 - 2.5f * f2 + 1.0f) + w2;
    float p12 = pm + w2 / s.w12;
    float fl  = floorf(p12);
    s.t = p12 - fl;
    int m = (int)pm, i12 = (int)fl;
    s.mA = m - 1; s.m1 = i12; s.m2 = i12 + 1; s.mB = m + 2;
    return s;
}

__global__ __launch_bounds__(256, 4) void taa_kernel(
    const float* __restrict__ x, const float* __restrict__ mv,
    const float* __restrict__ hist, float* __restrict__ out)
{
    constexpr int N = 2, H = 1080, W = 1920, HW = H * W;
    constexpr int NTX = W / TW;          // 30
    constexpr int NTY = H / TH;          // 135
    constexpr int NWG = N * NTX * NTY;   // 8100
    constexpr int Q = NWG / 8, R = NWG % 8;

    __shared__ float Lh[3][HROWS][HCOLS];

    // Bijective XCD swizzle (m204 form): each XCD gets a contiguous band of
    // x-major work ids -> vertically adjacent tiles share an XCD's L2.
    int d = blockIdx.x;
    int xcd = d & 7, di = d >> 3;
    int work = (xcd < R ? xcd * (Q + 1) : R * (Q + 1) + (xcd - R) * Q) + di;
    int n   = work / (NTX * NTY);
    int rem = work - n * (NTX * NTY);
    int ty  = rem / NTX;
    int tx  = rem - ty * NTX;
    const int w0 = tx * TW, h0 = ty * TH;

    const int lx = threadIdx.x & 63;
    const int wv = threadIdx.x >> 6;      // 0..3; thread owns rows 2wv, 2wv+1
    const int wpix = w0 + lx;
    const int hbase = h0 + 2 * wv;

    const float* hn = hist + n * 3 * HW;
    const float* xn = x    + n * 3 * HW;

    // ---- mv loads (coalesced float2, issue first) ----
    const float2 g0 = ((const float2*)mv)[n * HW + hbase * W + wpix];
    const float2 g1 = ((const float2*)mv)[n * HW + (hbase + 1) * W + wpix];

    // ---- stage history window into LDS ----
    const bool interior = (w0 >= 8) && (w0 + 71 <= W - 1) &&
                          (h0 >= 4) && (h0 + TH + 3 <= H - 1);
    if (interior) {
        float4* Lh4 = (float4*)&Lh[0][0][0];
        for (int idx = threadIdx.x; idx < 960; idx += 256) {      // 3*16*20
            int c  = idx / 320;
            int rm = idx - c * 320;
            int r  = rm / 20;
            int c4 = rm - r * 20;
            const float* src = hn + c * HW + (h0 - 4 + r) * W + (w0 - 8) + c4 * 4;
            Lh4[idx] = *(const float4*)src;
        }
    } else {
        float* LhF = &Lh[0][0][0];
        for (int idx = threadIdx.x; idx < 3840; idx += 256) {     // 3*16*80
            int c  = idx / 1280;
            int rm = idx - c * 1280;
            int r  = rm / 80;
            int cc = rm - r * 80;
            int gr = iclamp(h0 - 4 + r, 0, H - 1);
            int gc = iclamp(w0 - 8 + cc, 0, W - 1);
            LhF[idx] = hn[c * HW + gr * W + gc];
        }
    }

    // ---- x neighborhood via coalesced global loads (VMEM pipe, overlaps staging) ----
    // rows 2wv-1 .. 2wv+2 (4 rows shared by the 2 pixels)
    int rg0 = iclamp(hbase - 1, 0, H - 1) * W;
    int rg1 = hbase * W;
    int rg2 = (hbase + 1) * W;
    int rg3 = iclamp(hbase + 2, 0, H - 1) * W;
    const int wm = max(wpix - 1, 0), wp = min(wpix + 1, W - 1);

    float hmx[3][4], hmn[3][4], xmid[3][4];
#pragma unroll
    for (int c = 0; c < 3; ++c) {
        const float* xc = xn + c * HW;
        const int rg[4] = {rg0, rg1, rg2, rg3};
#pragma unroll
        for (int rr = 0; rr < 4; ++rr) {
            float a = xc[rg[rr] + wm];
            float b = xc[rg[rr] + wpix];
            float e = xc[rg[rr] + wp];
            hmx[c][rr]  = fmaxf(fmaxf(a, b), e);
            hmn[c][rr]  = fminf(fminf(a, b), e);
            xmid[c][rr] = b;
        }
    }

    // ---- bicubic setup for both pixels (overlaps staging latency) ----
    Setup sx0 = axis_setup(g0.x, (float)W);
    Setup sy0 = axis_setup(g0.y, (float)H);
    Setup sx1 = axis_setup(g1.x, (float)W);
    Setup sy1 = axis_setup(g1.y, (float)H);

    __syncthreads();

    float* on = out + n * 3 * HW;

#pragma unroll
    for (int p = 0; p < 2; ++p) {
        const Setup& sx = p ? sx1 : sx0;
        const Setup& sy = p ? sy1 : sy0;

        const int lrA = iclamp(sy.mA - (h0 - 4), 0, HROWS - 1);
        const int lr1 = iclamp(sy.m1 - (h0 - 4), 0, HROWS - 1);
        const int lr2 = iclamp(sy.m2 - (h0 - 4), 0, HROWS - 1);
        const int lrB = iclamp(sy.mB - (h0 - 4), 0, HROWS - 1);
        const int lcA = iclamp(sx.mA - (w0 - 8), 0, HCOLS - 1);
        const int lc1 = iclamp(sx.m1 - (w0 - 8), 0, HCOLS - 1);
        const int lc2 = iclamp(sx.m2 - (w0 - 8), 0, HCOLS - 1);
        const int lcB = iclamp(sx.mB - (w0 - 8), 0, HCOLS - 1);

        const float tx_ = sx.t, ty_ = sy.t;
        const float omtx = 1.0f - tx_, omty = 1.0f - ty_;
        const float ww1 = sx.w12 * sy.w0;
        const float ww2 = sx.w0  * sy.w12;
        const float ww3 = sx.w3  * sy.w12;
        const float ww4 = sx.w12 * sy.w3;
        const float ww5 = sx.w12 * sy.w12;
        const float rrec = 1.0f / (ww1 + ww2 + ww3 + ww4 + ww5);

        const int gpix = (hbase + p) * W + wpix;

#pragma unroll
        for (int c = 0; c < 3; ++c) {
            const float* rA = &Lh[c][lrA][0];
            const float* r1 = &Lh[c][lr1][0];
            const float* r2 = &Lh[c][lr2][0];
            const float* rB = &Lh[c][lrB][0];
            float s1   = rA[lc1] * omtx + rA[lc2] * tx_;
            float s4   = rB[lc1] * omtx + rB[lc2] * tx_;
            float s2   = r1[lcA] * omty + r2[lcA] * ty_;
            float s3   = r1[lcB] * omty + r2[lcB] * ty_;
            float top5 = r1[lc1] * omtx + r1[lc2] * tx_;
            float bot5 = r2[lc1] * omtx + r2[lc2] * tx_;
            float s5   = top5 * omty + bot5 * ty_;
            float reproj = (s1 * ww1 + s2 * ww2 + s3 * ww3 + s4 * ww4 + s5 * ww5) * rrec;

            // 3x3 clamp: rows p..p+2 of the shared 4-row min/max
            float mxv = fmaxf(fmaxf(hmx[c][p], hmx[c][p + 1]), hmx[c][p + 2]);
            float mnv = fminf(fminf(hmn[c][p], hmn[c][p + 1]), hmn[c][p + 2]);
            reproj = fminf(fmaxf(reproj, mnv), mxv);

            on[c * HW + gpix] = ALPHA * xmid[c][p + 1] + (1.0f - ALPHA) * reproj;
        }
    }
}

extern "C" void kernel_launch(void* const* d_in, const int* in_sizes, int n_in,
                              void* d_out, int out_size, void* d_ws, size_t ws_size,
                              hipStream_t stream) {
    const float* x    = (const float*)d_in[0];
    const float* mv   = (const float*)d_in[1];
    const float* hist = (const float*)d_in[2];
    float* out = (float*)d_out;

    constexpr int NWG = 2 * (1920 / TW) * (1080 / TH);  // 8100
    taa_kernel<<<dim3(NWG, 1, 1), dim3(256, 1, 1), 0, stream>>>(x, mv, hist, out);
}

// Round 5
// 48.123 us; speedup vs baseline: 5.2129x; 1.1224x over previous
//
#include <hip/hip_runtime.h>

static constexpr float ALPHA = 0.1f;

#define TW 64
#define TH 8
// hist window: rows h0-4 .. h0+11 (16 rows), cols w0-8 .. w0+75 (84 cols)
// jitter: |dx| < 4.8 px, |dy| < 2.7 px -> taps within [w-6,w+6] x [h-4,h+4]
#define HROWS 16
#define HCOLS 84          // row stride 84 ≡ 20 (mod 32 banks): Δrow=2 no longer collides
#define CHOFF (HROWS * HCOLS)   // 1344 floats; byte offset 5376*c fits ds_read imm

__device__ __forceinline__ int iclamp(int v, int lo, int hi) { return min(max(v, lo), hi); }

struct Setup {
    int mA, m1, m2, mB;   // global tap coords (unclamped)
    float t, w0, w3, w12;
};

__device__ __forceinline__ Setup axis_setup(float gcoord, float S) {
    Setup s;
    float pos = (gcoord + 1.0f) * 0.5f * S;
    float pm  = floorf(pos - 0.5f);
    float f   = pos - (pm + 0.5f);
    float f2 = f * f, f3 = f2 * f;
    s.w0  = -0.5f * f3 + f2 - 0.5f * f;
    float w2 = -1.5f * f3 + 2.0f * f2 + 0.5f * f;
    s.w3  =  0.5f * f3 - 0.5f * f2;
    s.w12 = (1.5f * f3 - 2.5f * f2 + 1.0f) + w2;
    float p12 = pm + w2 / s.w12;
    float fl  = floorf(p12);
    s.t = p12 - fl;
    int m = (int)pm, i12 = (int)fl;
    s.mA = m - 1; s.m1 = i12; s.m2 = i12 + 1; s.mB = m + 2;
    return s;
}

__global__ __launch_bounds__(256, 4) void taa_kernel(
    const float* __restrict__ x, const float* __restrict__ mv,
    const float* __restrict__ hist, float* __restrict__ out)
{
    constexpr int N = 2, H = 1080, W = 1920, HW = H * W;
    constexpr int NTX = W / TW;          // 30
    constexpr int NTY = H / TH;          // 135
    constexpr int NWG = N * NTX * NTY;   // 8100
    constexpr int Q = NWG / 8, R = NWG % 8;

    __shared__ __align__(16) float Lh[3 * CHOFF];

    // Bijective XCD swizzle: each XCD owns a contiguous band of x-major work
    // ids -> vertically adjacent tiles share an XCD's L2.
    int d = blockIdx.x;
    int xcd = d & 7, di = d >> 3;
    int work = (xcd < R ? xcd * (Q + 1) : R * (Q + 1) + (xcd - R) * Q) + di;
    int n   = work / (NTX * NTY);
    int rem = work - n * (NTX * NTY);
    int ty  = rem / NTX;
    int tx  = rem - ty * NTX;
    const int w0 = tx * TW, h0 = ty * TH;

    const int lx = threadIdx.x & 63;
    const int wv = threadIdx.x >> 6;      // 0..3; thread owns rows 2wv, 2wv+1
    const int wpix = w0 + lx;
    const int hbase = h0 + 2 * wv;

    const float* hn = hist + n * 3 * HW;
    const float* xn = x    + n * 3 * HW;

    // ---- mv loads (coalesced float2, issue first) ----
    const float2 g0 = ((const float2*)mv)[n * HW + hbase * W + wpix];
    const float2 g1 = ((const float2*)mv)[n * HW + (hbase + 1) * W + wpix];

    // ---- stage history window into LDS ----
    const bool interior = (tx >= 1) && (tx <= NTX - 2) &&
                          (h0 >= 4) && (h0 + TH + 3 <= H - 1);
    if (interior) {
        float4* Lh4 = (float4*)Lh;
        for (int idx = threadIdx.x; idx < 1008; idx += 256) {     // 3*16*21
            int c  = idx / 336;
            int rm = idx - c * 336;
            int r  = rm / 21;
            int c4 = rm - r * 21;
            const float* src = hn + c * HW + (h0 - 4 + r) * W + (w0 - 8) + c4 * 4;
            Lh4[idx] = *(const float4*)src;
        }
    } else {
        for (int idx = threadIdx.x; idx < 4032; idx += 256) {     // 3*16*84
            int c  = idx / CHOFF;
            int rm = idx - c * CHOFF;
            int r  = rm / HCOLS;
            int cc = rm - r * HCOLS;
            int gr = iclamp(h0 - 4 + r, 0, H - 1);
            int gc = iclamp(w0 - 8 + cc, 0, W - 1);
            Lh[idx] = hn[c * HW + gr * W + gc];
        }
    }

    // ---- x neighborhood (coalesced VMEM; overlaps staging latency) ----
    int rg0 = iclamp(hbase - 1, 0, H - 1) * W;
    int rg1 = hbase * W;
    int rg2 = (hbase + 1) * W;
    int rg3 = iclamp(hbase + 2, 0, H - 1) * W;
    const int rg[4] = {rg0, rg1, rg2, rg3};

    float hmx[3][4], hmn[3][4], xmid[3][4];
    if (tx >= 1 && tx <= NTX - 2) {
        // interior in x: wpix-1 / wpix+1 valid -> immediate-offset loads
#pragma unroll
        for (int c = 0; c < 3; ++c) {
            const float* xc = xn + c * HW + wpix;
#pragma unroll
            for (int rr = 0; rr < 4; ++rr) {
                const float* p = xc + rg[rr];
                float a = p[-1], b = p[0], e = p[1];
                hmx[c][rr]  = fmaxf(fmaxf(a, b), e);
                hmn[c][rr]  = fminf(fminf(a, b), e);
                xmid[c][rr] = b;
            }
        }
    } else {
        const int wm = max(wpix - 1, 0), wp = min(wpix + 1, W - 1);
#pragma unroll
        for (int c = 0; c < 3; ++c) {
            const float* xc = xn + c * HW;
#pragma unroll
            for (int rr = 0; rr < 4; ++rr) {
                float a = xc[rg[rr] + wm];
                float b = xc[rg[rr] + wpix];
                float e = xc[rg[rr] + wp];
                hmx[c][rr]  = fmaxf(fmaxf(a, b), e);
                hmn[c][rr]  = fminf(fminf(a, b), e);
                xmid[c][rr] = b;
            }
        }
    }

    // ---- bicubic setup for both pixels (overlaps staging latency) ----
    Setup sx0 = axis_setup(g0.x, (float)W);
    Setup sy0 = axis_setup(g0.y, (float)H);
    Setup sx1 = axis_setup(g1.x, (float)W);
    Setup sy1 = axis_setup(g1.y, (float)H);

    __syncthreads();

    float* on = out + n * 3 * HW;

#pragma unroll
    for (int p = 0; p < 2; ++p) {
        const Setup& sx = p ? sx1 : sx0;
        const Setup& sy = p ? sy1 : sy0;

        const int lrA = iclamp(sy.mA - (h0 - 4), 0, HROWS - 1);
        const int lr1 = iclamp(sy.m1 - (h0 - 4), 0, HROWS - 1);
        const int lr2 = iclamp(sy.m2 - (h0 - 4), 0, HROWS - 1);
        const int lrB = iclamp(sy.mB - (h0 - 4), 0, HROWS - 1);
        const int lcA = iclamp(sx.mA - (w0 - 8), 0, HCOLS - 1);
        const int lc1 = iclamp(sx.m1 - (w0 - 8), 0, HCOLS - 1);
        const int lc2 = iclamp(sx.m2 - (w0 - 8), 0, HCOLS - 1);
        const int lcB = iclamp(sx.mB - (w0 - 8), 0, HCOLS - 1);

        // 12 word offsets, shared across channels (channel adds a CONSTANT
        // 5376-byte ds_read immediate offset)
        const int rA = lrA * HCOLS, r1 = lr1 * HCOLS, r2 = lr2 * HCOLS, rB = lrB * HCOLS;
        const int oA1 = rA + lc1, oA2 = rA + lc2;
        const int o1A = r1 + lcA, o11 = r1 + lc1, o12 = r1 + lc2, o1B = r1 + lcB;
        const int o2A = r2 + lcA, o21 = r2 + lc1, o22 = r2 + lc2, o2B = r2 + lcB;
        const int oB1 = rB + lc1, oB2 = rB + lc2;

        const float tx_ = sx.t, ty_ = sy.t;
        const float omtx = 1.0f - tx_, omty = 1.0f - ty_;
        const float ww1 = sx.w12 * sy.w0;
        const float ww2 = sx.w0  * sy.w12;
        const float ww3 = sx.w3  * sy.w12;
        const float ww4 = sx.w12 * sy.w3;
        const float ww5 = sx.w12 * sy.w12;
        const float rrec = 1.0f / (ww1 + ww2 + ww3 + ww4 + ww5);

        const int gpix = (hbase + p) * W + wpix;

#pragma unroll
        for (int c = 0; c < 3; ++c) {
            const float* L = Lh + c * CHOFF;
            float s1   = L[oA1] * omtx + L[oA2] * tx_;
            float s4   = L[oB1] * omtx + L[oB2] * tx_;
            float s2   = L[o1A] * omty + L[o2A] * ty_;
            float s3   = L[o1B] * omty + L[o2B] * ty_;
            float top5 = L[o11] * omtx + L[o12] * tx_;
            float bot5 = L[o21] * omtx + L[o22] * tx_;
            float s5   = top5 * omty + bot5 * ty_;
            float reproj = (s1 * ww1 + s2 * ww2 + s3 * ww3 + s4 * ww4 + s5 * ww5) * rrec;

            float mxv = fmaxf(fmaxf(hmx[c][p], hmx[c][p + 1]), hmx[c][p + 2]);
            float mnv = fminf(fminf(hmn[c][p], hmn[c][p + 1]), hmn[c][p + 2]);
            reproj = fminf(fmaxf(reproj, mnv), mxv);

            on[c * HW + gpix] = ALPHA * xmid[c][p + 1] + (1.0f - ALPHA) * reproj;
        }
    }
}

extern "C" void kernel_launch(void* const* d_in, const int* in_sizes, int n_in,
                              void* d_out, int out_size, void* d_ws, size_t ws_size,
                              hipStream_t stream) {
    const float* x    = (const float*)d_in[0];
    const float* mv   = (const float*)d_in[1];
    const float* hist = (const float*)d_in[2];
    float* out = (float*)d_out;

    constexpr int NWG = 2 * (1920 / TW) * (1080 / TH);  // 8100
    taa_kernel<<<dim3(NWG, 1, 1), dim3(256, 1, 1), 0, stream>>>(x, mv, hist, out);
}